// Round 3
// baseline (1978.010 us; speedup 1.0000x reference)
//
#include <hip/hip_runtime.h>

typedef unsigned short u16;
typedef unsigned int   u32;

#define B_  64
#define T_  300
#define V_  25
#define C_  64
#define ROWS (B_*T_)          // 19200
#define ROWE (V_*C_)          // 1600
#define NSTAT 480000.0f       // B*T*V
#define EPS_ 1e-5f
#define TTILE 30              // k4_write time tile (10 tiles of 30)

__device__ __forceinline__ float b2f(u16 u) {
    union { u32 i; float f; } v; v.i = ((u32)u) << 16; return v.f;
}
__device__ __forceinline__ u16 f2b(float f) {  // round-to-nearest-even
    union { float f; u32 i; } v; v.f = f;
    u32 x = v.i;
    u32 r = x + 0x7fffu + ((x >> 16) & 1u);
    return (u16)(r >> 16);
}

// dtype-adaptive input load: F32 -> reinterpret as float*, else bf16 u16.
template<bool F32>
__device__ __forceinline__ float ldv(const void* p, size_t i) {
    if (F32) return ((const float*)p)[i];
    return b2f(((const u16*)p)[i]);
}

// out1 staging row stride in u16 units (fp32 mode: staging row r sits in the
// low half of fp32 output row r's byte range -> in-place overwrite is safe).
template<bool F32> struct Geo { static const int STR = F32 ? 3200 : 1600; };

// ---------------------------------------------------------------------------
// K0: dtype detection. Read W1's first 4096 u16 as bf16; fp32 data's low
// halves have uniform exponent bits -> max blows past 1e10 w.p. ~1.
// ---------------------------------------------------------------------------
__global__ void k0_detect(const void* W1raw, int* flag)
{
    __shared__ float red[256];
    const u16* p = (const u16*)W1raw;
    float mx = 0.0f;
    for (int i = threadIdx.x; i < 4096; i += 256) {
        float v = fabsf(b2f(p[i]));
        if (v == v) mx = fmaxf(mx, v);   // ignore NaN patterns
    }
    red[threadIdx.x] = mx;
    __syncthreads();
    for (int s = 128; s > 0; s >>= 1) {
        if (threadIdx.x < s) red[threadIdx.x] = fmaxf(red[threadIdx.x], red[threadIdx.x + s]);
        __syncthreads();
    }
    if (threadIdx.x == 0) flag[0] = (red[0] > 1e10f) ? 1 : 0;
}

// ---------------------------------------------------------------------------
// K1: normalized adjacencies An[3][25][28] (padded, pad=0) and bsum=b1+b2+b3.
// ---------------------------------------------------------------------------
template<bool F32>
__global__ void k1_prep(const int* __restrict__ flag,
                        const void* A, const void* E,
                        const void* b1, const void* b2, const void* b3,
                        float* __restrict__ an, float* __restrict__ bsum)
{
    if (flag[0] != (F32 ? 1 : 0)) return;
    __shared__ float dinvL[75];
    const int tid = threadIdx.x;
    if (tid < 75) {
        int i = tid / 25, v = tid % 25;
        float d = 1.0f;                       // diagonal forced to 1
        for (int u = 0; u < 25; ++u)
            if (u != v) d += ldv<F32>(A, (i*25+v)*25+u) * ldv<F32>(E, (i*25+v)*25+u);
        dinvL[tid] = (d > 0.0f) ? rsqrtf(d) : 0.0f;
    }
    __syncthreads();
    for (int idx = tid; idx < 2112; idx += 128) {
        float val = 0.0f;
        if (idx < 2100) {
            int i = idx / 700, rem = idx % 700, v = rem / 28, u = rem % 28;
            if (u < 25) {
                float ad = (u == v) ? 1.0f
                         : ldv<F32>(A, (i*25+v)*25+u) * ldv<F32>(E, (i*25+v)*25+u);
                val = dinvL[i*25+v] * ad * dinvL[i*25+u];
            }
        }
        an[idx] = val;
    }
    if (tid < 64) bsum[tid] = ldv<F32>(b1, tid) + ldv<F32>(b2, tid) + ldv<F32>(b3, tid);
}

// ---------------------------------------------------------------------------
// K2: spatial block. Per row (b,t): out1 = sum_i An_i @ (x @ W_i) + bsum.
// Writes out1 bf16 (staged in d_out at stride STR), accumulates BN partials.
// ---------------------------------------------------------------------------
template<bool F32>
__global__ __launch_bounds__(256) void k2_spatial(
    const int* __restrict__ flag, const void* x,
    const void* W1, const void* W2, const void* W3,
    const float* __restrict__ an, const float* __restrict__ bsum,
    u16* out1, float* __restrict__ p1)
{
    if (flag[0] != (F32 ? 1 : 0)) return;
    const int STR = Geo<F32>::STR;

    __shared__ float wL[4096];        // current branch W, [k][c]
    __shared__ float anL[2112];       // [3][25][28]
    __shared__ float xL[1600];        // current row x, [u][k]
    __shared__ float xwL[25*68];      // x@W_i, [u][c] pad 68
    __shared__ float redL[512];

    const int tid = threadIdx.x, c = tid & 63, g = tid >> 6;
    const int r0 = blockIdx.x * 10;

    for (int i2 = tid; i2 < 2112; i2 += 256) anL[i2] = an[i2];
    for (int i2 = tid; i2 < 4096; i2 += 256) wL[i2] = ldv<F32>(W1, i2);
    for (int i2 = tid; i2 < 1600; i2 += 256) xL[i2] = ldv<F32>(x, (size_t)r0*ROWE + i2);
    const float bsv = bsum[c];
    float ssum = 0.0f, ssq = 0.0f;
    __syncthreads();

    for (int rr = 0; rr < 10; ++rr) {
        const int row = r0 + rr;
        float acc2[7];
        #pragma unroll
        for (int j = 0; j < 7; ++j) acc2[j] = bsv;

        for (int br = 0; br < 3; ++br) {
            // ---- GEMM1: xw[u][c] = sum_k x[u][k] * Wbr[k][c] ----
            float acc[7];
            #pragma unroll
            for (int j = 0; j < 7; ++j) acc[j] = 0.0f;
            #pragma unroll 4
            for (int k4 = 0; k4 < 16; ++k4) {
                const int k = k4 * 4;
                const float w0 = wL[(k+0)*64+c], w1 = wL[(k+1)*64+c];
                const float w2 = wL[(k+2)*64+c], w3 = wL[(k+3)*64+c];
                #pragma unroll
                for (int j = 0; j < 7; ++j) {
                    const int u = g + 4*j;
                    if (u < 25) {
                        const float4 xv = *(const float4*)&xL[u*64+k];
                        acc[j] = fmaf(xv.x, w0, fmaf(xv.y, w1,
                                 fmaf(xv.z, w2, fmaf(xv.w, w3, acc[j]))));
                    }
                }
            }
            #pragma unroll
            for (int j = 0; j < 7; ++j) {
                const int u = g + 4*j;
                if (u < 25) xwL[u*68+c] = acc[j];
            }
            __syncthreads();   // xw visible; wL/xL readers done

            // ---- next-W load (overlaps A' phase) ----
            const void* Wnext = (br == 0) ? W2 : ((br == 1) ? W3 : W1);
            for (int i2 = tid; i2 < 4096; i2 += 256) wL[i2] = ldv<F32>(Wnext, i2);

            // ---- A': acc2[v][c] += sum_u An_br[v][u] * xw[u][c] ----
            float xv[25];
            #pragma unroll
            for (int u = 0; u < 25; ++u) xv[u] = xwL[u*68+c];
            #pragma unroll
            for (int j = 0; j < 7; ++j) {
                const int v = g + 4*j;
                if (v < 25) {
                    const float* ar = &anL[(br*25+v)*28];
                    float a0 = 0.0f;
                    #pragma unroll
                    for (int u4 = 0; u4 < 6; ++u4) {
                        const float4 a4 = *(const float4*)&ar[u4*4];
                        a0 = fmaf(a4.x, xv[u4*4+0], a0);
                        a0 = fmaf(a4.y, xv[u4*4+1], a0);
                        a0 = fmaf(a4.z, xv[u4*4+2], a0);
                        a0 = fmaf(a4.w, xv[u4*4+3], a0);
                    }
                    a0 = fmaf(ar[24], xv[24], a0);
                    acc2[j] += a0;
                }
            }

            if (br == 2) {
                #pragma unroll
                for (int j = 0; j < 7; ++j) {
                    const int v = g + 4*j;
                    if (v < 25) {
                        const float zz = acc2[j];
                        ssum += zz; ssq += zz * zz;
                        out1[(size_t)row*STR + v*64 + c] = f2b(zz);
                    }
                }
                if (rr < 9) {
                    for (int i2 = tid; i2 < 1600; i2 += 256)
                        xL[i2] = ldv<F32>(x, (size_t)(row+1)*ROWE + i2);
                }
            }
            __syncthreads();   // new wL (and xL on br==2) ready; xwL free
        }
    }

    redL[g*64+c] = ssum; redL[256+g*64+c] = ssq;
    __syncthreads();
    if (tid < 64) {
        float s = redL[tid] + redL[64+tid] + redL[128+tid] + redL[192+tid];
        p1[(size_t)blockIdx.x*128 + tid] = s;
    } else if (tid < 128) {
        const int cc = tid - 64;
        float s = redL[256+cc] + redL[320+cc] + redL[384+cc] + redL[448+cc];
        p1[(size_t)blockIdx.x*128 + 64 + cc] = s;
    }
}

// ---------------------------------------------------------------------------
// K3/K5: finalize BN stats -> scale/shift per channel
// ---------------------------------------------------------------------------
template<bool F32>
__global__ void k_bnstats(const int* __restrict__ flag,
                          const float* __restrict__ part, int nblk,
                          const void* gamma, const void* beta,
                          float* __restrict__ scale, float* __restrict__ shift)
{
    if (flag[0] != (F32 ? 1 : 0)) return;
    __shared__ float redL[512];
    const int tid = threadIdx.x, c = tid & 63, q = tid >> 6;
    float s = 0.0f, ss = 0.0f;
    for (int p = q; p < nblk; p += 4) { s += part[p*128+c]; ss += part[p*128+64+c]; }
    redL[q*64+c] = s; redL[256+q*64+c] = ss;
    __syncthreads();
    if (tid < 64) {
        const float S  = redL[tid] + redL[64+tid] + redL[128+tid] + redL[192+tid];
        const float SS = redL[256+tid] + redL[320+tid] + redL[384+tid] + redL[448+tid];
        const float m   = S / NSTAT;
        const float var = SS / NSTAT - m*m;
        const float rstd = rsqrtf(var + EPS_);
        const float sc = ldv<F32>(gamma, tid) * rstd;
        scale[tid] = sc;
        shift[tid] = ldv<F32>(beta, tid) - m * sc;
    }
}

// ---------------------------------------------------------------------------
// K_halo: save boundary out1 rows (t%30 in {0..3, 26..29}) into ws so the
// in-place k4_write pass can read cross-tile halos after neighbors overwrite.
// ---------------------------------------------------------------------------
template<bool F32>
__global__ __launch_bounds__(128) void k_halo(const int* __restrict__ flag,
                                              const u16* out1, u16* halo)
{
    if (flag[0] != (F32 ? 1 : 0)) return;
    const int STR = Geo<F32>::STR;
    const int id = blockIdx.x;            // 64*10*8 = 5120
    const int slot = id & 7, tile = (id >> 3) % 10, b = id / 80;
    const int t = tile * TTILE + (slot < 4 ? slot : slot + 22);
    const uint4* src = (const uint4*)&out1[((size_t)b*T_ + t) * STR];
    uint4* dst = (uint4*)&halo[(size_t)id * ROWE];
    for (int j = threadIdx.x; j < 200; j += 128) dst[j] = src[j];
}

template<bool F32>
__device__ __forceinline__ const u16* row_ptr(const u16* out1, const u16* halo,
                                              int b, int s, int t0)
{
    if (s >= t0 && s < t0 + TTILE)
        return &out1[((size_t)b*T_ + s) * Geo<F32>::STR];
    const int tile = s / TTILE, rem = s % TTILE;
    const int slot = rem < 4 ? rem : rem - 22;
    return &halo[(((size_t)b*10 + tile)*8 + slot) * ROWE];
}

// ---------------------------------------------------------------------------
// K4a (stats): h = relu(bn1(out1)); sliding band-sum; z = hsum@Wt + bt;
// accumulate BN2 partials ONLY (no z store).
// ---------------------------------------------------------------------------
template<bool F32>
__global__ __launch_bounds__(256) void k4_stats(
    const int* __restrict__ flag,
    const u16* out1, const void* Wt, const void* bt,
    const float* __restrict__ sc1, const float* __restrict__ sh1,
    float* __restrict__ p2)
{
    if (flag[0] != (F32 ? 1 : 0)) return;
    const int STR = Geo<F32>::STR;

    __shared__ u16   ring[10*1600];
    __shared__ float haccL[1600];
    __shared__ float wtL[4096];
    __shared__ float redL[512];

    const int tid = threadIdx.x, c = tid & 63, g = tid >> 6;
    const int b = blockIdx.y, t0 = blockIdx.x * 15;
    const float s1 = sc1[c], h1 = sh1[c];
    const float btv = ldv<F32>(bt, c);

    for (int i2 = tid; i2 < 4096; i2 += 256) wtL[i2] = ldv<F32>(Wt, i2);
    for (int i2 = tid; i2 < 1600; i2 += 256) haccL[i2] = 0.0f;
    __syncthreads();

    float zsum = 0.0f, zsq = 0.0f;

    {   // initial window [t0-4, t0+4]
        int slo = t0 - 4; if (slo < 0) slo = 0;
        const int shi = t0 + 4;            // <= 289
        for (int s = slo; s <= shi; ++s) {
            const u16* xr = &out1[((size_t)b*T_ + s) * STR];
            for (int jj = tid; jj < 1600; jj += 256) {   // jj&63 == c
                float hv = fmaf(b2f(xr[jj]), s1, h1);
                hv = hv > 0.0f ? hv : 0.0f;
                const u16 hb = f2b(hv);
                ring[(s%10)*1600 + jj] = hb;
                haccL[jj] += b2f(hb);
            }
        }
    }
    __syncthreads();

    for (int t = t0; t < t0 + 15; ++t) {
        if (t > t0) {
            const int snew = t + 4, sold = t - 5;
            if (snew < T_) {
                const u16* xr = &out1[((size_t)b*T_ + snew) * STR];
                for (int jj = tid; jj < 1600; jj += 256) {
                    float hv = fmaf(b2f(xr[jj]), s1, h1);
                    hv = hv > 0.0f ? hv : 0.0f;
                    const u16 hb = f2b(hv);
                    ring[(snew%10)*1600 + jj] = hb;
                    haccL[jj] += b2f(hb);
                }
            }
            if (sold >= 0) {
                for (int jj = tid; jj < 1600; jj += 256)
                    haccL[jj] -= b2f(ring[(sold%10)*1600 + jj]);
            }
            __syncthreads();
        }

        float acc[7];
        #pragma unroll
        for (int j = 0; j < 7; ++j) acc[j] = btv;
        #pragma unroll 4
        for (int k4 = 0; k4 < 16; ++k4) {
            const int k = k4 * 4;
            const float w0 = wtL[(k+0)*64+c], w1 = wtL[(k+1)*64+c];
            const float w2 = wtL[(k+2)*64+c], w3 = wtL[(k+3)*64+c];
            #pragma unroll
            for (int j = 0; j < 7; ++j) {
                const int v = g + 4*j;
                if (v < 25) {
                    const float4 hv4 = *(const float4*)&haccL[v*64+k];
                    acc[j] = fmaf(hv4.x, w0, fmaf(hv4.y, w1,
                             fmaf(hv4.z, w2, fmaf(hv4.w, w3, acc[j]))));
                }
            }
        }
        #pragma unroll
        for (int j = 0; j < 7; ++j) {
            const int v = g + 4*j;
            if (v < 25) { const float zz = acc[j]; zsum += zz; zsq += zz * zz; }
        }
        __syncthreads();   // hacc reads done before next window update
    }

    redL[g*64+c] = zsum; redL[256+g*64+c] = zsq;
    __syncthreads();
    const int blk = blockIdx.y * 20 + blockIdx.x;
    if (tid < 64) {
        float s = redL[tid] + redL[64+tid] + redL[128+tid] + redL[192+tid];
        p2[(size_t)blk*128 + tid] = s;
    } else if (tid < 128) {
        const int cc = tid - 64;
        float s = redL[256+cc] + redL[320+cc] + redL[384+cc] + redL[448+cc];
        p2[(size_t)blk*128 + 64 + cc] = s;
    }
}

// ---------------------------------------------------------------------------
// K4b (write): recompute z, apply bn2+relu, write final output to d_out IN
// PLACE over the staging (bf16 mode: same rows; fp32 mode: fp32 row r's bytes
// cover staging row r exactly). Cross-tile halo rows come from ws copy.
// Within a tile, row t is written >=4 barriers after its last staging read.
// ---------------------------------------------------------------------------
template<bool F32>
__global__ __launch_bounds__(256) void k4_write(
    const int* __restrict__ flag,
    const u16* out1, const u16* halo,
    const void* Wt, const void* bt,
    const float* __restrict__ sc1, const float* __restrict__ sh1,
    const float* __restrict__ sc2, const float* __restrict__ sh2,
    void* outp)
{
    if (flag[0] != (F32 ? 1 : 0)) return;

    __shared__ u16   ring[10*1600];
    __shared__ float haccL[1600];
    __shared__ float wtL[4096];

    const int tid = threadIdx.x, c = tid & 63, g = tid >> 6;
    const int b = blockIdx.y, t0 = blockIdx.x * TTILE;
    const float s1 = sc1[c], h1 = sh1[c];
    const float s2 = sc2[c], h2 = sh2[c];
    const float btv = ldv<F32>(bt, c);

    for (int i2 = tid; i2 < 4096; i2 += 256) wtL[i2] = ldv<F32>(Wt, i2);
    for (int i2 = tid; i2 < 1600; i2 += 256) haccL[i2] = 0.0f;
    __syncthreads();

    {   // initial window [t0-4, t0+4]
        int slo = t0 - 4; if (slo < 0) slo = 0;
        const int shi = t0 + 4;
        for (int s = slo; s <= shi; ++s) {
            const u16* xr = row_ptr<F32>(out1, halo, b, s, t0);
            for (int jj = tid; jj < 1600; jj += 256) {
                float hv = fmaf(b2f(xr[jj]), s1, h1);
                hv = hv > 0.0f ? hv : 0.0f;
                const u16 hb = f2b(hv);
                ring[(s%10)*1600 + jj] = hb;
                haccL[jj] += b2f(hb);
            }
        }
    }
    __syncthreads();

    for (int t = t0; t < t0 + TTILE; ++t) {
        if (t > t0) {
            const int snew = t + 4, sold = t - 5;
            if (snew < T_) {
                const u16* xr = row_ptr<F32>(out1, halo, b, snew, t0);
                for (int jj = tid; jj < 1600; jj += 256) {
                    float hv = fmaf(b2f(xr[jj]), s1, h1);
                    hv = hv > 0.0f ? hv : 0.0f;
                    const u16 hb = f2b(hv);
                    ring[(snew%10)*1600 + jj] = hb;
                    haccL[jj] += b2f(hb);
                }
            }
            if (sold >= 0) {
                for (int jj = tid; jj < 1600; jj += 256)
                    haccL[jj] -= b2f(ring[(sold%10)*1600 + jj]);
            }
            __syncthreads();
        }

        float acc[7];
        #pragma unroll
        for (int j = 0; j < 7; ++j) acc[j] = btv;
        #pragma unroll 4
        for (int k4 = 0; k4 < 16; ++k4) {
            const int k = k4 * 4;
            const float w0 = wtL[(k+0)*64+c], w1 = wtL[(k+1)*64+c];
            const float w2 = wtL[(k+2)*64+c], w3 = wtL[(k+3)*64+c];
            #pragma unroll
            for (int j = 0; j < 7; ++j) {
                const int v = g + 4*j;
                if (v < 25) {
                    const float4 hv4 = *(const float4*)&haccL[v*64+k];
                    acc[j] = fmaf(hv4.x, w0, fmaf(hv4.y, w1,
                             fmaf(hv4.z, w2, fmaf(hv4.w, w3, acc[j]))));
                }
            }
        }
        const size_t rowbase = ((size_t)b*T_ + t) * ROWE;
        #pragma unroll
        for (int j = 0; j < 7; ++j) {
            const int v = g + 4*j;
            if (v < 25) {
                float o = fmaf(acc[j], s2, h2);
                o = o > 0.0f ? o : 0.0f;
                if (F32) ((float*)outp)[rowbase + v*64 + c] = o;
                else     ((u16*)outp)[rowbase + v*64 + c] = f2b(o);
            }
        }
        __syncthreads();   // staging/hacc reads done before next update
    }
}

// ---------------------------------------------------------------------------
extern "C" void kernel_launch(void* const* d_in, const int* in_sizes, int n_in,
                              void* d_out, int out_size, void* d_ws, size_t ws_size,
                              hipStream_t stream)
{
    const void* x     = d_in[0];
    const void* A     = d_in[1];
    const void* E     = d_in[2];
    const void* W1    = d_in[3];
    const void* b1    = d_in[4];
    const void* W2    = d_in[5];
    const void* b2    = d_in[6];
    const void* W3    = d_in[7];
    const void* b3    = d_in[8];
    const void* Wt    = d_in[9];
    const void* bt    = d_in[10];
    const void* gamma = d_in[11];
    const void* beta  = d_in[12];

    u16* out1 = (u16*)d_out;          // stage-1 bf16 staging lives in d_out

    // ws layout — front of d_ws; total ≈ 18.1 MB.
    int*   flag = (int*)d_ws;
    float* wsf  = (float*)d_ws;
    float* an   = wsf + 4;            // 16B offset
    float* bsum = an + 2112;
    float* sc1  = bsum + 64;
    float* sh1  = sc1 + 64;
    float* sc2  = sh1 + 64;
    float* sh2  = sc2 + 64;
    float* p1   = sh2 + 64;           // 1920*128
    float* p2   = p1 + 1920*128;      // 1280*128
    u16*  halo  = (u16*)(p2 + 1280*128);   // 5120*1600 u16 = 16.4 MB

    hipLaunchKernelGGL(k0_detect, dim3(1), dim3(256), 0, stream, W1, flag);

    hipLaunchKernelGGL(k1_prep<false>, dim3(1), dim3(128), 0, stream,
                       flag, A, E, b1, b2, b3, an, bsum);
    hipLaunchKernelGGL(k1_prep<true>, dim3(1), dim3(128), 0, stream,
                       flag, A, E, b1, b2, b3, an, bsum);

    hipLaunchKernelGGL(k2_spatial<false>, dim3(1920), dim3(256), 0, stream,
                       flag, x, W1, W2, W3, an, bsum, out1, p1);
    hipLaunchKernelGGL(k2_spatial<true>, dim3(1920), dim3(256), 0, stream,
                       flag, x, W1, W2, W3, an, bsum, out1, p1);

    hipLaunchKernelGGL(k_bnstats<false>, dim3(1), dim3(256), 0, stream,
                       flag, p1, 1920, gamma, beta, sc1, sh1);
    hipLaunchKernelGGL(k_bnstats<true>, dim3(1), dim3(256), 0, stream,
                       flag, p1, 1920, gamma, beta, sc1, sh1);

    hipLaunchKernelGGL(k_halo<false>, dim3(5120), dim3(128), 0, stream,
                       flag, out1, halo);
    hipLaunchKernelGGL(k_halo<true>, dim3(5120), dim3(128), 0, stream,
                       flag, out1, halo);

    hipLaunchKernelGGL(k4_stats<false>, dim3(20, 64), dim3(256), 0, stream,
                       flag, out1, Wt, bt, sc1, sh1, p2);
    hipLaunchKernelGGL(k4_stats<true>, dim3(20, 64), dim3(256), 0, stream,
                       flag, out1, Wt, bt, sc1, sh1, p2);

    hipLaunchKernelGGL(k_bnstats<false>, dim3(1), dim3(256), 0, stream,
                       flag, p2, 1280, gamma, beta, sc2, sh2);
    hipLaunchKernelGGL(k_bnstats<true>, dim3(1), dim3(256), 0, stream,
                       flag, p2, 1280, gamma, beta, sc2, sh2);

    hipLaunchKernelGGL(k4_write<false>, dim3(10, 64), dim3(256), 0, stream,
                       flag, out1, halo, Wt, bt, sc1, sh1, sc2, sh2, d_out);
    hipLaunchKernelGGL(k4_write<true>, dim3(10, 64), dim3(256), 0, stream,
                       flag, out1, halo, Wt, bt, sc1, sh1, sc2, sh2, d_out);
}